// Round 2
// baseline (24.274 us; speedup 1.0000x reference)
//
#include <hip/hip_runtime.h>
#include <hip/hip_bf16.h>

typedef __attribute__((ext_vector_type(4))) float f32x4;
typedef __attribute__((ext_vector_type(8))) short bf16x8;
typedef __attribute__((ext_vector_type(4))) short bf16x4;

#define DEVFN static __device__ __forceinline__

constexpr int Mdim = 4096;
constexpr int Ndim = 512;
constexpr int Dk   = 512;
constexpr float W_S = 0.6224593312018546f;   // sigmoid(0.5)
constexpr float W_L = 1.0f - W_S;

DEVFN short f2bf(float x) {
    __hip_bfloat16 h = __float2bfloat16(x);   // RNE
    return *reinterpret_cast<short*>(&h);
}

// ============================ prepass ============================
// Builds in ws:  Abf [4096][1024] bf16  (S ++ L, k-concat)
//                Bbf [512][1024]  bf16  (W_S*Ws ++ W_L*Wl)  -- blend folded
//                biasf [512] f32        (W_S*bs + W_L*bl)
constexpr int A_UNITS    = (Mdim * 2 * Dk) / 8;   // 524288 units of 8 elems
constexpr int B_UNITS    = (Ndim * 2 * Dk) / 8;   // 65536
constexpr int BIAS_UNITS = Ndim / 8;              // 64
constexpr int TOT_UNITS  = A_UNITS + B_UNITS + BIAS_UNITS;
constexpr size_t ABF_BYTES  = (size_t)Mdim * 2 * Dk * 2;   // 8 MB
constexpr size_t BBF_BYTES  = (size_t)Ndim * 2 * Dk * 2;   // 1 MB
constexpr size_t WS_NEEDED  = ABF_BYTES + BBF_BYTES + Ndim * 4;

__global__ __launch_bounds__(256)
void prepass_kernel(const float* __restrict__ S, const float* __restrict__ L,
                    const float* __restrict__ Ws, const float* __restrict__ Wl,
                    const float* __restrict__ bs, const float* __restrict__ bl,
                    short* __restrict__ Abf, short* __restrict__ Bbf,
                    float* __restrict__ biasf)
{
    int t = blockIdx.x * blockDim.x + threadIdx.x;
    if (t >= TOT_UNITS) return;
    if (t < A_UNITS) {
        const int row = t >> 7;
        const int col = (t & 127) * 8;            // 0..1016, within one half
        const float* src = (col < Dk) ? (S + (size_t)row * Dk + col)
                                      : (L + (size_t)row * Dk + col - Dk);
        float4 v0 = *(const float4*)src;
        float4 v1 = *(const float4*)(src + 4);
        bf16x8 o = { f2bf(v0.x), f2bf(v0.y), f2bf(v0.z), f2bf(v0.w),
                     f2bf(v1.x), f2bf(v1.y), f2bf(v1.z), f2bf(v1.w) };
        *(bf16x8*)(Abf + (size_t)t * 8) = o;
    } else if (t < A_UNITS + B_UNITS) {
        const int u   = t - A_UNITS;
        const int row = u >> 7;
        const int col = (u & 127) * 8;
        const bool sm = (col < Dk);
        const float* src = sm ? (Ws + (size_t)row * Dk + col)
                              : (Wl + (size_t)row * Dk + col - Dk);
        const float sc = sm ? W_S : W_L;
        float4 v0 = *(const float4*)src;
        float4 v1 = *(const float4*)(src + 4);
        bf16x8 o = { f2bf(v0.x*sc), f2bf(v0.y*sc), f2bf(v0.z*sc), f2bf(v0.w*sc),
                     f2bf(v1.x*sc), f2bf(v1.y*sc), f2bf(v1.z*sc), f2bf(v1.w*sc) };
        *(bf16x8*)(Bbf + (size_t)u * 8) = o;
    } else {
        const int u = t - A_UNITS - B_UNITS;
        const int j = u * 8;
        float4 s0 = *(const float4*)(bs + j), s1 = *(const float4*)(bs + j + 4);
        float4 l0 = *(const float4*)(bl + j), l1 = *(const float4*)(bl + j + 4);
        float4 o0 = { W_S*s0.x + W_L*l0.x, W_S*s0.y + W_L*l0.y,
                      W_S*s0.z + W_L*l0.z, W_S*s0.w + W_L*l0.w };
        float4 o1 = { W_S*s1.x + W_L*l1.x, W_S*s1.y + W_L*l1.y,
                      W_S*s1.z + W_L*l1.z, W_S*s1.w + W_L*l1.w };
        *(float4*)(biasf + j)     = o0;
        *(float4*)(biasf + j + 4) = o1;
    }
}

// ============================ bf16 GEMM ============================
// C[4096][512] = Abf[4096][1024] @ Bbf[512][1024]^T + biasf
// BM=128 BN=64 BK=64, 512 thr (8 waves: 4M x 2N), grid 256 (1/CU).
// LDS: linear dest for global_load_lds; swizzle applied on the GLOBAL source
// (rule #21) and again on ds_read: byte ^= (row&7)<<4 within each 128B row.
constexpr int NKT = (2 * Dk) / 64;   // 16 K-steps

__global__ __launch_bounds__(512, 2)
void gemm_bf16_kernel(const short* __restrict__ Abf, const short* __restrict__ Bbf,
                      const float* __restrict__ biasf, float* __restrict__ out)
{
    // per buffer: A 128x64 bf16 = 16KB at 0, B 64x64 bf16 = 8KB at 16KB
    __shared__ char sm[2][24 * 1024];

    const int tid = threadIdx.x;
    const int bid = blockIdx.x;
    const int Mtile = bid & 31;          // XCD = bid%8 = Mtile%8 -> A panel per-XCD
    const int Ntile = bid >> 5;
    const int Mbase = Mtile * 128;
    const int Nbase = Ntile * 64;

    const int lane = tid & 63;
    const int wid  = tid >> 6;           // 0..7
    const int wr   = wid >> 1;           // 0..3
    const int wc   = wid & 1;            // 0..1

    // Staging: issue covers 1KB of LDS = 8 rows x 128B. lane l -> row +l/8,
    // colByte (l&7)*16. Inverse swizzle on source: ^ ((row&7)<<4), row&7 = l>>3.
    const int lrow = lane >> 3;                         // 0..7
    const int lsw  = (((lane & 7) ^ lrow) << 4);        // swizzled col byte
    const char* pA = (const char*)Abf + ((size_t)Mbase + lrow) * 2048 + lsw;
    const char* pB = (const char*)Bbf + ((size_t)Nbase + lrow) * 2048 + lsw;

    auto stage = [&](int p, int kt) {
        const int kb = kt * 128;   // 64 bf16 along k
#pragma unroll
        for (int q = 0; q < 2; ++q) {
            __builtin_amdgcn_global_load_lds(
                (const __attribute__((address_space(1))) void*)(pA + (size_t)(wid * 2 + q) * 8 * 2048 + kb),
                (__attribute__((address_space(3))) void*)(&sm[p][(wid * 2 + q) * 1024]),
                16, 0, 0);
        }
        __builtin_amdgcn_global_load_lds(
            (const __attribute__((address_space(1))) void*)(pB + (size_t)wid * 8 * 2048 + kb),
            (__attribute__((address_space(3))) void*)(&sm[p][16 * 1024 + wid * 1024]),
            16, 0, 0);
    };

    f32x4 acc[2][2];
#pragma unroll
    for (int m = 0; m < 2; ++m)
#pragma unroll
        for (int n = 0; n < 2; ++n) acc[m][n] = (f32x4)0.0f;

    stage(0, 0);

#pragma unroll 2
    for (int kt = 0; kt < NKT; ++kt) {
        const int p = kt & 1;
        __syncthreads();                 // drains vmcnt -> buf p ready; prev reads done
        if (kt + 1 < NKT) stage(p ^ 1, kt + 1);   // overlaps with compute below
#pragma unroll
        for (int kk = 0; kk < 2; ++kk) {
            const int kbyte = kk * 64 + (lane >> 4) * 16;
            bf16x8 a[2], b[2];
#pragma unroll
            for (int m = 0; m < 2; ++m) {
                const int row = wr * 32 + m * 16 + (lane & 15);
                a[m] = *(const bf16x8*)(&sm[p][row * 128 + (kbyte ^ ((row & 7) << 4))]);
            }
#pragma unroll
            for (int n = 0; n < 2; ++n) {
                const int row = wc * 32 + n * 16 + (lane & 15);
                b[n] = *(const bf16x8*)(&sm[p][16 * 1024 + row * 128 + (kbyte ^ ((row & 7) << 4))]);
            }
#pragma unroll
            for (int m = 0; m < 2; ++m)
#pragma unroll
                for (int n = 0; n < 2; ++n)
                    acc[m][n] = __builtin_amdgcn_mfma_f32_16x16x32_bf16(a[m], b[n], acc[m][n], 0, 0, 0);
        }
    }

    // Epilogue: D layout col=lane&15, row=(lane>>4)*4+r (verified m89/m91).
#pragma unroll
    for (int n = 0; n < 2; ++n) {
        const int j = Nbase + wc * 32 + n * 16 + (lane & 15);
        const float bias = biasf[j];
#pragma unroll
        for (int m = 0; m < 2; ++m) {
            const int i0 = Mbase + wr * 32 + m * 16 + ((lane >> 4) << 2);
#pragma unroll
            for (int r = 0; r < 4; ++r)
                out[(size_t)(i0 + r) * Ndim + j] = acc[m][n][r] + bias;
        }
    }
}

// ==================== fallback (round-1 fused kernel) ====================
DEVFN int swz_fb(int row, int colByte) { return row * 128 + (colByte ^ ((row & 7) << 4)); }

__global__ __launch_bounds__(512, 2)
void fused_proj_kernel(const float* __restrict__ S, const float* __restrict__ L,
                       const float* __restrict__ Ws, const float* __restrict__ Wl,
                       const float* __restrict__ bs, const float* __restrict__ bl,
                       float* __restrict__ out)
{
    __shared__ char smA[2][128 * 64 * 2];
    __shared__ char smB[2][64 * 64 * 2];
    const int tid = threadIdx.x, bid = blockIdx.x;
    const int Mbase = (bid & 31) * 128, Nbase = (bid >> 5) * 64;
    const int srow = tid >> 4, scol = (tid & 15) * 4;
    const int lane = tid & 63, wid = tid >> 6, wr = wid >> 1, wc = wid & 1;

    f32x4 acc[2][2];
#pragma unroll
    for (int m = 0; m < 2; ++m)
#pragma unroll
        for (int n = 0; n < 2; ++n) acc[m][n] = (f32x4)0.0f;
    float4 av[4]; float4 bv[2];

    auto loadTiles = [&](int kt) {
        const float* sA = (kt < 8) ? S : L;
        const float* sB = (kt < 8) ? Ws : Wl;
        const int kOff = (kt & 7) * 64 + scol;
#pragma unroll
        for (int q = 0; q < 4; ++q)
            av[q] = *(const float4*)(sA + (size_t)(Mbase + q * 32 + srow) * Dk + kOff);
#pragma unroll
        for (int q = 0; q < 2; ++q)
            bv[q] = *(const float4*)(sB + (size_t)(Nbase + q * 32 + srow) * Dk + kOff);
    };
    auto writeTiles = [&](int p, float scB) {
#pragma unroll
        for (int q = 0; q < 4; ++q) {
            bf16x4 v = { f2bf(av[q].x), f2bf(av[q].y), f2bf(av[q].z), f2bf(av[q].w) };
            *(bf16x4*)(&smA[p][swz_fb(q * 32 + srow, scol * 2)]) = v;
        }
#pragma unroll
        for (int q = 0; q < 2; ++q) {
            bf16x4 v = { f2bf(bv[q].x * scB), f2bf(bv[q].y * scB),
                         f2bf(bv[q].z * scB), f2bf(bv[q].w * scB) };
            *(bf16x4*)(&smB[p][swz_fb(q * 32 + srow, scol * 2)]) = v;
        }
    };

    loadTiles(0); writeTiles(0, W_S); loadTiles(1);
    __syncthreads();
    for (int kt = 0; kt < 16; ++kt) {
        const int p = kt & 1;
#pragma unroll
        for (int kk = 0; kk < 2; ++kk) {
            bf16x8 a[2], b[2];
            const int cb = kk * 64 + (lane >> 4) * 16;
#pragma unroll
            for (int m = 0; m < 2; ++m)
                a[m] = *(const bf16x8*)(&smA[p][swz_fb(wr * 32 + m * 16 + (lane & 15), cb)]);
#pragma unroll
            for (int n = 0; n < 2; ++n)
                b[n] = *(const bf16x8*)(&smB[p][swz_fb(wc * 32 + n * 16 + (lane & 15), cb)]);
#pragma unroll
            for (int m = 0; m < 2; ++m)
#pragma unroll
                for (int n = 0; n < 2; ++n)
                    acc[m][n] = __builtin_amdgcn_mfma_f32_16x16x32_bf16(a[m], b[n], acc[m][n], 0, 0, 0);
        }
        if (kt + 1 < 16) {
            writeTiles(p ^ 1, (kt + 1 < 8) ? W_S : W_L);
            if (kt + 2 < 16) loadTiles(kt + 2);
            __syncthreads();
        }
    }
#pragma unroll
    for (int n = 0; n < 2; ++n) {
        const int j = Nbase + wc * 32 + n * 16 + (lane & 15);
        const float bias = W_S * bs[j] + W_L * bl[j];
#pragma unroll
        for (int m = 0; m < 2; ++m) {
            const int i0 = Mbase + wr * 32 + m * 16 + ((lane >> 4) << 2);
#pragma unroll
            for (int r = 0; r < 4; ++r)
                out[(size_t)(i0 + r) * Ndim + j] = acc[m][n][r] + bias;
        }
    }
}

extern "C" void kernel_launch(void* const* d_in, const int* in_sizes, int n_in,
                              void* d_out, int out_size, void* d_ws, size_t ws_size,
                              hipStream_t stream) {
    const float* S  = (const float*)d_in[0];
    const float* L  = (const float*)d_in[1];
    const float* Ws = (const float*)d_in[2];
    const float* bs = (const float*)d_in[3];
    const float* Wl = (const float*)d_in[4];
    const float* bl = (const float*)d_in[5];
    // d_in[6] = sigma: dead code in reference output.

    if (ws_size >= WS_NEEDED) {
        short* Abf   = (short*)d_ws;
        short* Bbf   = (short*)((char*)d_ws + ABF_BYTES);
        float* biasf = (float*)((char*)d_ws + ABF_BYTES + BBF_BYTES);
        const int pre_blocks = (TOT_UNITS + 255) / 256;
        prepass_kernel<<<pre_blocks, 256, 0, stream>>>(S, L, Ws, Wl, bs, bl, Abf, Bbf, biasf);
        gemm_bf16_kernel<<<256, 512, 0, stream>>>(Abf, Bbf, biasf, (float*)d_out);
    } else {
        fused_proj_kernel<<<256, 512, 0, stream>>>(S, L, Ws, Wl, bs, bl, (float*)d_out);
    }
}

// Round 3
// 21.209 us; speedup vs baseline: 1.1445x; 1.1445x over previous
//
#include <hip/hip_runtime.h>
#include <hip/hip_bf16.h>

typedef __attribute__((ext_vector_type(4))) float f32x4;
typedef __attribute__((ext_vector_type(8))) short bf16x8;
typedef __attribute__((ext_vector_type(4))) short bf16x4;

#define DEVFN static __device__ __forceinline__

constexpr int Mdim = 4096;
constexpr int Ndim = 512;
constexpr int Dk   = 512;
constexpr float W_S = 0.6224593312018546f;   // sigmoid(0.5)
constexpr float W_L = 1.0f - W_S;

DEVFN short f2bf(float x) {
    __hip_bfloat16 h = __float2bfloat16(x);   // RNE; compiler emits pk form
    return *reinterpret_cast<short*>(&h);
}

// ============================ prepass ============================
// ws:  Abf [4096][1024] bf16 (S ++ L k-concat)
//      Bbf [512][1024] bf16  (W_S*Ws ++ W_L*Wl; blend folded)
//      biasf [512] f32       (W_S*bs + W_L*bl)
constexpr int A_UNITS    = (Mdim * 2 * Dk) / 8;
constexpr int B_UNITS    = (Ndim * 2 * Dk) / 8;
constexpr int BIAS_UNITS = Ndim / 8;
constexpr int TOT_UNITS  = A_UNITS + B_UNITS + BIAS_UNITS;
constexpr size_t ABF_BYTES  = (size_t)Mdim * 2 * Dk * 2;
constexpr size_t BBF_BYTES  = (size_t)Ndim * 2 * Dk * 2;
constexpr size_t WS_NEEDED  = ABF_BYTES + BBF_BYTES + Ndim * 4;

__global__ __launch_bounds__(256)
void prepass_kernel(const float* __restrict__ S, const float* __restrict__ L,
                    const float* __restrict__ Ws, const float* __restrict__ Wl,
                    const float* __restrict__ bs, const float* __restrict__ bl,
                    short* __restrict__ Abf, short* __restrict__ Bbf,
                    float* __restrict__ biasf)
{
    int t = blockIdx.x * blockDim.x + threadIdx.x;
    if (t >= TOT_UNITS) return;
    if (t < A_UNITS) {
        const int row = t >> 7;
        const int col = (t & 127) * 8;
        const float* src = (col < Dk) ? (S + (size_t)row * Dk + col)
                                      : (L + (size_t)row * Dk + col - Dk);
        float4 v0 = *(const float4*)src;
        float4 v1 = *(const float4*)(src + 4);
        bf16x8 o = { f2bf(v0.x), f2bf(v0.y), f2bf(v0.z), f2bf(v0.w),
                     f2bf(v1.x), f2bf(v1.y), f2bf(v1.z), f2bf(v1.w) };
        *(bf16x8*)(Abf + (size_t)t * 8) = o;
    } else if (t < A_UNITS + B_UNITS) {
        const int u   = t - A_UNITS;
        const int row = u >> 7;
        const int col = (u & 127) * 8;
        const bool sm = (col < Dk);
        const float* src = sm ? (Ws + (size_t)row * Dk + col)
                              : (Wl + (size_t)row * Dk + col - Dk);
        const float sc = sm ? W_S : W_L;
        float4 v0 = *(const float4*)src;
        float4 v1 = *(const float4*)(src + 4);
        bf16x8 o = { f2bf(v0.x*sc), f2bf(v0.y*sc), f2bf(v0.z*sc), f2bf(v0.w*sc),
                     f2bf(v1.x*sc), f2bf(v1.y*sc), f2bf(v1.z*sc), f2bf(v1.w*sc) };
        *(bf16x8*)(Bbf + (size_t)u * 8) = o;
    } else {
        const int u = t - A_UNITS - B_UNITS;
        const int j = u * 8;
        float4 s0 = *(const float4*)(bs + j), s1 = *(const float4*)(bs + j + 4);
        float4 l0 = *(const float4*)(bl + j), l1 = *(const float4*)(bl + j + 4);
        float4 o0 = { W_S*s0.x + W_L*l0.x, W_S*s0.y + W_L*l0.y,
                      W_S*s0.z + W_L*l0.z, W_S*s0.w + W_L*l0.w };
        float4 o1 = { W_S*s1.x + W_L*l1.x, W_S*s1.y + W_L*l1.y,
                      W_S*s1.z + W_L*l1.z, W_S*s1.w + W_L*l1.w };
        *(float4*)(biasf + j)     = o0;
        *(float4*)(biasf + j + 4) = o1;
    }
}

// ============================ bf16 GEMM ============================
// C[4096][512] = Abf @ Bbf^T + biasf.  BM=BN=64, BK=64.
// 256 thr (4 waves 2x2, wave=32x32), grid 512 = 2 blocks/CU.
// 3-buffer LDS ring, depth-2 prefetch, counted vmcnt(4) (never 0 mid-loop).
constexpr int NKT = (2 * Dk) / 64;   // 16

__global__ __launch_bounds__(256, 2)
void gemm_bf16_kernel(const short* __restrict__ Abf, const short* __restrict__ Bbf,
                      const float* __restrict__ biasf, float* __restrict__ out)
{
    // buffer: A 64x64 bf16 (8KB) @0, B 64x64 bf16 (8KB) @8K. 3 bufs = 48KB.
    __shared__ char sm[3][16 * 1024];

    const int tid = threadIdx.x;
    const int bid = blockIdx.x;
    const int Mtile = bid & 63;          // XCD = bid%8 = Mtile%8: 8 A-panels/XCD = 1MB + B 1MB -> L2-fits
    const int Ntile = bid >> 6;
    const int Mbase = Mtile * 64;
    const int Nbase = Ntile * 64;

    const int lane = tid & 63;
    const int wid  = tid >> 6;           // 0..3
    const int wr   = wid >> 1;           // 0..1
    const int wc   = wid & 1;            // 0..1

    // global_load_lds: linear LDS dest (base + lane*16); inverse swizzle on the
    // GLOBAL source (rule #21). Chunk = 1KB = 8 rows x 128B. Wave wid stages
    // rows [wid*16, wid*16+16) of both A and B tiles.
    const int lrow = lane >> 3;                       // 0..7
    const int lsw  = (((lane & 7) ^ lrow) << 4);      // pre-swizzled col byte
    const char* pA = (const char*)Abf + ((size_t)(Mbase + wid * 16) + lrow) * 2048 + lsw;
    const char* pB = (const char*)Bbf + ((size_t)(Nbase + wid * 16) + lrow) * 2048 + lsw;

    auto stage = [&](int p, int kt) {
        const int kb = kt * 128;   // byte offset of this K-step
#pragma unroll
        for (int q = 0; q < 2; ++q) {
            __builtin_amdgcn_global_load_lds(
                (const __attribute__((address_space(1))) void*)(pA + (size_t)q * 8 * 2048 + kb),
                (__attribute__((address_space(3))) void*)(&sm[p][(wid * 2 + q) * 1024]),
                16, 0, 0);
            __builtin_amdgcn_global_load_lds(
                (const __attribute__((address_space(1))) void*)(pB + (size_t)q * 8 * 2048 + kb),
                (__attribute__((address_space(3))) void*)(&sm[p][8 * 1024 + (wid * 2 + q) * 1024]),
                16, 0, 0);
        }
    };

    f32x4 acc[2][2];
#pragma unroll
    for (int m = 0; m < 2; ++m)
#pragma unroll
        for (int n = 0; n < 2; ++n) acc[m][n] = (f32x4)0.0f;

    stage(0, 0);
    stage(1, 1);

#pragma unroll
    for (int kt = 0; kt < NKT; ++kt) {
        const int p = kt % 3;
        // Wait for stage(kt) (oldest 4 loads); leave stage(kt+1)'s 4 in flight.
        if (kt < NKT - 1) asm volatile("s_waitcnt vmcnt(4)" ::: "memory");
        else              asm volatile("s_waitcnt vmcnt(0)" ::: "memory");
        __builtin_amdgcn_s_barrier();          // all waves' stage(kt) complete
        asm volatile("" ::: "memory");         // no LDS-read hoisting above barrier
        // Issue next prefetch AFTER barrier: its target buf (kt+2)%3 == (kt-1)%3
        // was last read in iter kt-1, whose readers all passed this barrier.
        if (kt + 2 < NKT) stage((kt + 2) % 3, kt + 2);
        __builtin_amdgcn_sched_barrier(0);     // pin issue-before-compute

#pragma unroll
        for (int kk = 0; kk < 2; ++kk) {
            const int kbyte = kk * 64 + (lane >> 4) * 16;
            bf16x8 a[2], b[2];
#pragma unroll
            for (int m = 0; m < 2; ++m) {
                const int row = wr * 32 + m * 16 + (lane & 15);
                a[m] = *(const bf16x8*)(&sm[p][row * 128 + (kbyte ^ ((row & 7) << 4))]);
            }
#pragma unroll
            for (int n = 0; n < 2; ++n) {
                const int row = wc * 32 + n * 16 + (lane & 15);
                b[n] = *(const bf16x8*)(&sm[p][8 * 1024 + row * 128 + (kbyte ^ ((row & 7) << 4))]);
            }
#pragma unroll
            for (int m = 0; m < 2; ++m)
#pragma unroll
                for (int n = 0; n < 2; ++n)
                    acc[m][n] = __builtin_amdgcn_mfma_f32_16x16x32_bf16(a[m], b[n], acc[m][n], 0, 0, 0);
        }
    }

    // D layout: col = lane&15, row = (lane>>4)*4 + r (verified m89/m91).
#pragma unroll
    for (int n = 0; n < 2; ++n) {
        const int j = Nbase + wc * 32 + n * 16 + (lane & 15);
        const float bias = biasf[j];
#pragma unroll
        for (int m = 0; m < 2; ++m) {
            const int i0 = Mbase + wr * 32 + m * 16 + ((lane >> 4) << 2);
#pragma unroll
            for (int r = 0; r < 4; ++r)
                out[(size_t)(i0 + r) * Ndim + j] = acc[m][n][r] + bias;
        }
    }
}

// ==================== fallback (round-1 fused kernel, proven 17.55us) ====================
DEVFN int swz_fb(int row, int colByte) { return row * 128 + (colByte ^ ((row & 7) << 4)); }

__global__ __launch_bounds__(512, 2)
void fused_proj_kernel(const float* __restrict__ S, const float* __restrict__ L,
                       const float* __restrict__ Ws, const float* __restrict__ Wl,
                       const float* __restrict__ bs, const float* __restrict__ bl,
                       float* __restrict__ out)
{
    __shared__ char smA[2][128 * 64 * 2];
    __shared__ char smB[2][64 * 64 * 2];
    const int tid = threadIdx.x, bid = blockIdx.x;
    const int Mbase = (bid & 31) * 128, Nbase = (bid >> 5) * 64;
    const int srow = tid >> 4, scol = (tid & 15) * 4;
    const int lane = tid & 63, wid = tid >> 6, wr = wid >> 1, wc = wid & 1;

    f32x4 acc[2][2];
#pragma unroll
    for (int m = 0; m < 2; ++m)
#pragma unroll
        for (int n = 0; n < 2; ++n) acc[m][n] = (f32x4)0.0f;
    float4 av[4]; float4 bv[2];

    auto loadTiles = [&](int kt) {
        const float* sA = (kt < 8) ? S : L;
        const float* sB = (kt < 8) ? Ws : Wl;
        const int kOff = (kt & 7) * 64 + scol;
#pragma unroll
        for (int q = 0; q < 4; ++q)
            av[q] = *(const float4*)(sA + (size_t)(Mbase + q * 32 + srow) * Dk + kOff);
#pragma unroll
        for (int q = 0; q < 2; ++q)
            bv[q] = *(const float4*)(sB + (size_t)(Nbase + q * 32 + srow) * Dk + kOff);
    };
    auto writeTiles = [&](int p, float scB) {
#pragma unroll
        for (int q = 0; q < 4; ++q) {
            bf16x4 v = { f2bf(av[q].x), f2bf(av[q].y), f2bf(av[q].z), f2bf(av[q].w) };
            *(bf16x4*)(&smA[p][swz_fb(q * 32 + srow, scol * 2)]) = v;
        }
#pragma unroll
        for (int q = 0; q < 2; ++q) {
            bf16x4 v = { f2bf(bv[q].x * scB), f2bf(bv[q].y * scB),
                         f2bf(bv[q].z * scB), f2bf(bv[q].w * scB) };
            *(bf16x4*)(&smB[p][swz_fb(q * 32 + srow, scol * 2)]) = v;
        }
    };

    loadTiles(0); writeTiles(0, W_S); loadTiles(1);
    __syncthreads();
    for (int kt = 0; kt < 16; ++kt) {
        const int p = kt & 1;
#pragma unroll
        for (int kk = 0; kk < 2; ++kk) {
            bf16x8 a[2], b[2];
            const int cb = kk * 64 + (lane >> 4) * 16;
#pragma unroll
            for (int m = 0; m < 2; ++m)
                a[m] = *(const bf16x8*)(&smA[p][swz_fb(wr * 32 + m * 16 + (lane & 15), cb)]);
#pragma unroll
            for (int n = 0; n < 2; ++n)
                b[n] = *(const bf16x8*)(&smB[p][swz_fb(wc * 32 + n * 16 + (lane & 15), cb)]);
#pragma unroll
            for (int m = 0; m < 2; ++m)
#pragma unroll
                for (int n = 0; n < 2; ++n)
                    acc[m][n] = __builtin_amdgcn_mfma_f32_16x16x32_bf16(a[m], b[n], acc[m][n], 0, 0, 0);
        }
        if (kt + 1 < 16) {
            writeTiles(p ^ 1, (kt + 1 < 8) ? W_S : W_L);
            if (kt + 2 < 16) loadTiles(kt + 2);
            __syncthreads();
        }
    }
#pragma unroll
    for (int n = 0; n < 2; ++n) {
        const int j = Nbase + wc * 32 + n * 16 + (lane & 15);
        const float bias = W_S * bs[j] + W_L * bl[j];
#pragma unroll
        for (int m = 0; m < 2; ++m) {
            const int i0 = Mbase + wr * 32 + m * 16 + ((lane >> 4) << 2);
#pragma unroll
            for (int r = 0; r < 4; ++r)
                out[(size_t)(i0 + r) * Ndim + j] = acc[m][n][r] + bias;
        }
    }
}

extern "C" void kernel_launch(void* const* d_in, const int* in_sizes, int n_in,
                              void* d_out, int out_size, void* d_ws, size_t ws_size,
                              hipStream_t stream) {
    const float* S  = (const float*)d_in[0];
    const float* L  = (const float*)d_in[1];
    const float* Ws = (const float*)d_in[2];
    const float* bs = (const float*)d_in[3];
    const float* Wl = (const float*)d_in[4];
    const float* bl = (const float*)d_in[5];
    // d_in[6] = sigma: dead code in reference output.

    if (ws_size >= WS_NEEDED) {
        short* Abf   = (short*)d_ws;
        short* Bbf   = (short*)((char*)d_ws + ABF_BYTES);
        float* biasf = (float*)((char*)d_ws + ABF_BYTES + BBF_BYTES);
        const int pre_blocks = (TOT_UNITS + 255) / 256;
        prepass_kernel<<<pre_blocks, 256, 0, stream>>>(S, L, Ws, Wl, bs, bl, Abf, Bbf, biasf);
        gemm_bf16_kernel<<<512, 256, 0, stream>>>(Abf, Bbf, biasf, (float*)d_out);
    } else {
        fused_proj_kernel<<<256, 512, 0, stream>>>(S, L, Ws, Wl, bs, bl, (float*)d_out);
    }
}